// Round 1
// baseline (593.831 us; speedup 1.0000x reference)
//
#include <hip/hip_runtime.h>

// Problem constants (fixed shapes from setup_inputs)
#define P_TOT   2048        // 8*256 positions
#define V       32000
#define D       100
#define DPAD    128         // padded N for 8 n-tiles of 16
#define TS      32          // positions per block
#define VSPLIT  10          // vocab splits
#define KB      3200        // V / VSPLIT
#define VC      128         // chunk columns
#define NCHUNK  25          // KB / VC
#define ASTRIDE 136         // VC + 8 (bf16 units) -> 272B rows, odd multiple of 16B
#define BSTRIDE 136

typedef __attribute__((ext_vector_type(8))) short short8;
typedef __attribute__((ext_vector_type(4))) float floatx4;

static __device__ __forceinline__ unsigned short f2bf(float x) {
    // round-to-nearest-even f32 -> bf16 (no NaN inputs here)
    unsigned u = __float_as_uint(x);
    u += 0x7FFFu + ((u >> 16) & 1u);
    return (unsigned short)(u >> 16);
}

// ---------------------------------------------------------------------------
// Kernel 0: W[32000][100] f32 -> Wt[128][32000] bf16 (transposed, zero-padded)
// ---------------------------------------------------------------------------
__global__ __launch_bounds__(256)
void k_prep(const float* __restrict__ W, unsigned short* __restrict__ Wt) {
    __shared__ float tile[64 * 133];   // 64 v  x 128 d, pad 133 (gcd(5,32)=1)
    const int vb = blockIdx.x * 64;
    const int tid = threadIdx.x;
    #pragma unroll
    for (int it = 0; it < 32; ++it) {
        int idx = it * 256 + tid;
        int d = idx & 127, vl = idx >> 7;
        float val = (d < D) ? W[(size_t)(vb + vl) * D + d] : 0.0f;
        tile[vl * 133 + d] = val;
    }
    __syncthreads();
    #pragma unroll
    for (int it = 0; it < 32; ++it) {
        int idx = it * 256 + tid;
        int vl = idx & 63, d = idx >> 6;
        Wt[(size_t)d * V + vb + vl] = f2bf(tile[vl * 133 + d]);
    }
}

// ---------------------------------------------------------------------------
// Kernel 1: fused online-softmax + gumbel + argmax + bf16 MFMA partial GEMM
// grid (64, 10): blockIdx.x = position tile (32 rows), blockIdx.y = vocab split
// ---------------------------------------------------------------------------
__global__ __launch_bounds__(256, 3)
void k_main(const float* __restrict__ logits, const float* __restrict__ gum,
            const unsigned short* __restrict__ Wt,
            float* __restrict__ Epart, float* __restrict__ stats) {
    __shared__ unsigned short Abuf[TS * ASTRIDE];     // p~ chunk, bf16
    __shared__ unsigned short Bbuf[DPAD * BSTRIDE];   // Wt chunk, bf16
    __shared__ __align__(16) float alphaS[TS];
    __shared__ float m2run[TS], s2run[TS], amaxv[TS];
    __shared__ int amaxi[TS];

    const int tid   = threadIdx.x;
    const int r     = tid >> 3;        // row 0..31
    const int q     = tid & 7;         // 8 lanes per row
    const int lane  = tid & 63;
    const int w     = tid >> 6;        // wave 0..3
    const int mtile = w & 1;           // M-tile (rows 0-15 / 16-31)
    const int ngrp  = w >> 1;          // N-group (cols 0-63 / 64-127)
    const int stile = blockIdx.x;
    const int vs    = blockIdx.y;

    const int grow = stile * TS + r;
    const size_t rowbase = (size_t)grow * V + (size_t)vs * KB;

    if (q == 0) {
        m2run[r] = -1e30f; s2run[r] = 0.0f;
        amaxv[r] = -1e30f; amaxi[r] = 0;
    }
    float m1 = -1e30f, sA = 0.0f, sB = 0.0f;   // online stats for log_softmax(logits)
    floatx4 acc[4];
    #pragma unroll
    for (int i = 0; i < 4; ++i) acc[i] = (floatx4){0.f, 0.f, 0.f, 0.f};

    for (int ch = 0; ch < NCHUNK; ++ch) {
        __syncthreads();   // barrier A: prev MFMA done with Abuf/Bbuf/alpha
        const int cbase = ch * VC;

        // ---- stage Wt chunk -> Bbuf (128 rows x 128 bf16) ----
        {
            const unsigned short* src = Wt + (size_t)vs * KB + cbase;
            #pragma unroll
            for (int it = 0; it < 8; ++it) {
                int idx = it * 256 + tid;          // 0..2047 = 128 rows x 16 segs
                int dd = idx >> 4, seg = idx & 15;
                uint4 vwt = *(const uint4*)(src + (size_t)dd * V + seg * 8);
                *(uint4*)(&Bbuf[dd * BSTRIDE + seg * 8]) = vwt;
            }
        }

        // ---- load logits/u, compute g, z ----
        float lg[16], zz[16];
        {
            const float* lptr = logits + rowbase + cbase + q * 4;
            const float* uptr = gum    + rowbase + cbase + q * 4;
            float4 l4[4], u4[4];
            #pragma unroll
            for (int k = 0; k < 4; ++k) l4[k] = *(const float4*)(lptr + (size_t)k * 32);
            #pragma unroll
            for (int k = 0; k < 4; ++k) u4[k] = *(const float4*)(uptr + (size_t)k * 32);
            #pragma unroll
            for (int k = 0; k < 4; ++k) {
                lg[k*4+0] = l4[k].x; lg[k*4+1] = l4[k].y;
                lg[k*4+2] = l4[k].z; lg[k*4+3] = l4[k].w;
                float uu[4] = {u4[k].x, u4[k].y, u4[k].z, u4[k].w};
                #pragma unroll
                for (int l = 0; l < 4; ++l) {
                    // precise logf: feeds argmax (must match JAX ordering)
                    float g = -logf(-logf(uu[l] + 1e-20f) + 1e-20f);
                    zz[k*4+l] = lg[k*4+l] + g;
                }
            }
        }

        // ---- online (m1, sum e, sum t*e) for entropy ----
        {
            float cm = lg[0];
            #pragma unroll
            for (int j = 1; j < 16; ++j) cm = fmaxf(cm, lg[j]);
            float m1n = fmaxf(m1, cm);
            float sc = __expf(m1 - m1n);                    // 0 on first chunk
            sB = (sB + sA * (m1 - m1n)) * sc;
            sA = sA * sc;
            m1 = m1n;
            #pragma unroll
            for (int j = 0; j < 16; ++j) {
                float t = lg[j] - m1;
                float e = __expf(t);
                sA += e; sB += t * e;
            }
        }

        // ---- chunk z max + first-index argmax, reduce over 8 q-lanes ----
        float cmv = -1e30f; int cmi = 0;
        #pragma unroll
        for (int k = 0; k < 4; ++k)
            #pragma unroll
            for (int l = 0; l < 4; ++l) {
                int j = k*4 + l;
                int gidx = vs * KB + cbase + k*32 + q*4 + l;  // ascending in j
                if (zz[j] > cmv) { cmv = zz[j]; cmi = gidx; }
            }
        #pragma unroll
        for (int m = 1; m < 8; m <<= 1) {
            float ov = __shfl_xor(cmv, m, 64);
            int   oi = __shfl_xor(cmi, m, 64);
            if (ov > cmv || (ov == cmv && oi < cmi)) { cmv = ov; cmi = oi; }
        }

        // ---- p~ = exp(z - m2new), write bf16 A-tile, update row state ----
        float m2old = m2run[r];            // safe: last write was pre-barrier-A
        float m2new = fmaxf(m2old, cmv);
        float csum = 0.0f;
        unsigned short pb[16];
        #pragma unroll
        for (int j = 0; j < 16; ++j) {
            float p = __expf(zz[j] - m2new);
            csum += p;
            pb[j] = f2bf(p);
        }
        #pragma unroll
        for (int k = 0; k < 4; ++k) {
            ushort4 v4 = make_ushort4(pb[k*4], pb[k*4+1], pb[k*4+2], pb[k*4+3]);
            *(ushort4*)(&Abuf[r * ASTRIDE + k*32 + q*4]) = v4;
        }
        #pragma unroll
        for (int m = 1; m < 8; m <<= 1) csum += __shfl_xor(csum, m, 64);
        if (q == 0) {
            float al = __expf(m2old - m2new);
            alphaS[r] = al;
            s2run[r] = s2run[r] * al + csum;
            m2run[r] = m2new;
            if (cmv > amaxv[r]) { amaxv[r] = cmv; amaxi[r] = cmi; }
        }

        __syncthreads();   // barrier B: Abuf/Bbuf/alpha ready

        // ---- rescale accumulators, MFMA over 4 k-steps x 4 n-tiles ----
        floatx4 al4 = *(const floatx4*)(&alphaS[mtile*16 + ((lane >> 4) << 2)]);
        #pragma unroll
        for (int nt = 0; nt < 4; ++nt) {
            acc[nt][0] *= al4[0]; acc[nt][1] *= al4[1];
            acc[nt][2] *= al4[2]; acc[nt][3] *= al4[3];
        }
        const int ka0 = (lane >> 4) << 3;  // quad*8
        const unsigned short* arow = &Abuf[(mtile*16 + (lane & 15)) * ASTRIDE + ka0];
        #pragma unroll
        for (int ks = 0; ks < 4; ++ks) {
            short8 a = *(const short8*)(arow + ks * 32);
            #pragma unroll
            for (int nt = 0; nt < 4; ++nt) {
                const unsigned short* brow =
                    &Bbuf[(ngrp*64 + nt*16 + (lane & 15)) * BSTRIDE + ka0 + ks*32];
                short8 b = *(const short8*)brow;
                acc[nt] = __builtin_amdgcn_mfma_f32_16x16x32_bf16(a, b, acc[nt], 0, 0, 0);
            }
        }
    }

    // ---- final: merge entropy stats across q-lanes, write partials ----
    #pragma unroll
    for (int m = 1; m < 8; m <<= 1) {
        float om = __shfl_xor(m1, m, 64);
        float oA = __shfl_xor(sA, m, 64);
        float oB = __shfl_xor(sB, m, 64);
        float mn = fmaxf(m1, om);
        float ea = __expf(m1 - mn), eb = __expf(om - mn);
        sB = (sB + sA * (m1 - mn)) * ea + (oB + oA * (om - mn)) * eb;
        sA = sA * ea + oA * eb;
        m1 = mn;
    }
    if (q == 0) {
        float* st = stats + ((size_t)grow * VSPLIT + vs) * 8;
        st[0] = m1; st[1] = sA; st[2] = sB;
        st[3] = m2run[r]; st[4] = s2run[r];
        st[5] = amaxv[r]; st[6] = __int_as_float(amaxi[r]); st[7] = 0.0f;
    }
    #pragma unroll
    for (int nt = 0; nt < 4; ++nt) {
        int n = ngrp*64 + nt*16 + (lane & 15);
        if (n < D) {
            #pragma unroll
            for (int i = 0; i < 4; ++i) {
                int row = mtile*16 + ((lane >> 4) << 2) + i;
                int pos = stile * TS + row;
                Epart[((size_t)pos * VSPLIT + vs) * D + n] = acc[nt][i];
            }
        }
    }
}

// ---------------------------------------------------------------------------
// Kernel 2: combine V-splits per position; write obf_word + obf_word_emb + ent
// ---------------------------------------------------------------------------
__global__ __launch_bounds__(128)
void k_combine(const float* __restrict__ stats, const float* __restrict__ Epart,
               const float* __restrict__ W, const int* __restrict__ inp,
               const int* __restrict__ msk, float* __restrict__ out,
               float* __restrict__ entbuf) {
    const int pos = blockIdx.x;
    const int t = threadIdx.x;
    const float* st = stats + (size_t)pos * VSPLIT * 8;

    // redundant uniform combine on all threads (scalar-cached)
    float m1 = -1e30f, sA = 0.0f, sB = 0.0f, m2g = -1e30f;
    float bestv = -1e30f; int besti = 0;
    #pragma unroll
    for (int p = 0; p < VSPLIT; ++p) {
        const float* s = st + p * 8;
        float om = s[0], oA = s[1], oB = s[2];
        float mn = fmaxf(m1, om);
        float ea = __expf(m1 - mn), eb = __expf(om - mn);
        sB = (sB + sA * (m1 - mn)) * ea + (oB + oA * (om - mn)) * eb;
        sA = sA * ea + oA * eb;
        m1 = mn;
        m2g = fmaxf(m2g, s[3]);
        float av = s[5];
        if (av > bestv) { bestv = av; besti = __float_as_int(s[6]); }  // split order = index order
    }
    float beta[VSPLIT];
    float s2g = 0.0f;
    #pragma unroll
    for (int p = 0; p < VSPLIT; ++p) {
        beta[p] = __expf(st[p*8 + 3] - m2g);
        s2g += st[p*8 + 4] * beta[p];
    }

    const int iw = inp[pos];
    const bool mk = msk[pos] != 0;
    const bool safe = besti != iw;

    if (t == 0) {
        int obf = mk ? (safe ? besti : 0) : iw;
        out[pos] = (float)obf;
        float ent = sB / sA - logf(sA);       // sum lp*exp(lp), shift-invariant
        entbuf[pos] = mk ? ent : 0.0f;
    }
    if (t < D) {
        float e = 0.0f;
        const float* ep = Epart + (size_t)pos * VSPLIT * D + t;
        #pragma unroll
        for (int p = 0; p < VSPLIT; ++p) e += ep[(size_t)p * D] * beta[p];
        e /= s2g;                              // sampled_emb[t]
        float val;
        if (mk) val = safe ? e : W[t];         // W[0][t] = unk_emb
        else    val = W[(size_t)iw * D + t];   // base_emb
        out[P_TOT + (size_t)pos * D + t] = val;
    }
}

// ---------------------------------------------------------------------------
// Kernel 3: ent_loss scalar
// ---------------------------------------------------------------------------
__global__ __launch_bounds__(256)
void k_final(const float* __restrict__ entbuf, const int* __restrict__ msk,
             float* __restrict__ out) {
    __shared__ float se[4], sm[4];
    const int t = threadIdx.x;
    float e = 0.0f, m = 0.0f;
    for (int i = t; i < P_TOT; i += 256) {
        e += entbuf[i];
        m += (float)msk[i];
    }
    #pragma unroll
    for (int k = 32; k >= 1; k >>= 1) {
        e += __shfl_down(e, k, 64);
        m += __shfl_down(m, k, 64);
    }
    if ((t & 63) == 0) { se[t >> 6] = e; sm[t >> 6] = m; }
    __syncthreads();
    if (t == 0) {
        float te = se[0] + se[1] + se[2] + se[3];
        float tm = sm[0] + sm[1] + sm[2] + sm[3];
        out[P_TOT + (size_t)P_TOT * D] = te / (tm * (float)V);
    }
}

// ---------------------------------------------------------------------------
extern "C" void kernel_launch(void* const* d_in, const int* in_sizes, int n_in,
                              void* d_out, int out_size, void* d_ws, size_t ws_size,
                              hipStream_t stream) {
    const float* logits = (const float*)d_in[0];
    const float* gum    = (const float*)d_in[1];
    const int*   inp    = (const int*)d_in[2];
    const int*   msk    = (const int*)d_in[3];
    const float* W      = (const float*)d_in[4];
    float* out = (float*)d_out;

    char* ws = (char*)d_ws;
    unsigned short* Wt  = (unsigned short*)ws;            // 128*32000*2 = 8,192,000 B
    float* Epart  = (float*)(ws + 8192000);               // 2048*10*100*4 = 8,192,000 B
    float* stats  = (float*)(ws + 16384000);              // 2048*10*8*4  =   655,360 B
    float* entbuf = (float*)(ws + 17039360);              // 2048*4       =     8,192 B

    k_prep<<<500, 256, 0, stream>>>(W, Wt);
    dim3 g1(P_TOT / TS, VSPLIT);
    k_main<<<g1, 256, 0, stream>>>(logits, gum, Wt, Epart, stats);
    k_combine<<<P_TOT, 128, 0, stream>>>(stats, Epart, W, inp, msk, out, entbuf);
    k_final<<<1, 256, 0, stream>>>(entbuf, msk, out);
}